// Round 1
// baseline (858.823 us; speedup 1.0000x reference)
//
#include <hip/hip_runtime.h>
#include <math.h>

#define B_    32
#define C_    64
#define O_    64
#define H_    128
#define W_    128
#define HYP_  64
#define KU_   (O_ * C_ * 9)   // 36864 kernel units per sample

// ---------------------------------------------------------------------------
// Kernel 1: per-sample conv weights  w_all[b][u] = tanh(hyp[b]·Wk[u] + bk[u])
// 144 blocks x 256 threads; one kernel-unit per thread, loop over 32 samples.
// ---------------------------------------------------------------------------
__global__ __launch_bounds__(256) void hyper_weights_kernel(
    const float* __restrict__ hyp,   // [32][64]
    const float* __restrict__ Wk,    // [36864][64]
    const float* __restrict__ bk,    // [36864]
    float* __restrict__ w_all)       // [32][36864]
{
    __shared__ float sh[B_ * HYP_];  // 8 KB
    const int tid = threadIdx.x;
    for (int i = tid; i < B_ * HYP_; i += 256) sh[i] = hyp[i];
    __syncthreads();

    const int u = blockIdx.x * 256 + tid;   // 0..36863 (exact: 144*256)
    float wr[HYP_];
    const float4* wp = reinterpret_cast<const float4*>(Wk + (size_t)u * HYP_);
    #pragma unroll
    for (int i = 0; i < HYP_ / 4; ++i) {
        float4 v = wp[i];
        wr[4 * i + 0] = v.x; wr[4 * i + 1] = v.y;
        wr[4 * i + 2] = v.z; wr[4 * i + 3] = v.w;
    }
    const float bku = bk[u];

    for (int b = 0; b < B_; ++b) {
        float acc = bku;
        #pragma unroll
        for (int h = 0; h < HYP_; ++h) acc += sh[b * HYP_ + h] * wr[h];
        w_all[(size_t)b * KU_ + u] = tanhf(acc);
    }
}

// ---------------------------------------------------------------------------
// Kernel 2: per-sample bias  bias_all[b][o] = tanh(hyp[b]·Wb[o] + bb[o])
// ---------------------------------------------------------------------------
__global__ __launch_bounds__(256) void hyper_bias_kernel(
    const float* __restrict__ hyp,   // [32][64]
    const float* __restrict__ Wb,    // [64][64]
    const float* __restrict__ bb,    // [64]
    float* __restrict__ bias_all)    // [32][64]
{
    const int idx = blockIdx.x * 256 + threadIdx.x;   // 0..2047
    const int b = idx >> 6;
    const int o = idx & 63;
    const float* hp = hyp + b * HYP_;
    const float* wp = Wb + o * HYP_;
    float acc = bb[o];
    #pragma unroll
    for (int h = 0; h < HYP_; ++h) acc += hp[h] * wp[h];
    bias_all[idx] = tanhf(acc);
}

// ---------------------------------------------------------------------------
// Kernel 3: per-sample 3x3 conv, fp32 direct, register-blocked.
// Block = 256 threads = one (sample, 16x16 spatial tile), all 64 out-channels.
// Thread = 8 out-channels x 8 pixels (64 fp32 accumulators).
// ---------------------------------------------------------------------------
#define CC_   8      // input-channel chunk staged in LDS
#define XPAD_ 20     // LDS x-tile row pitch (floats); 18 used + 2 pad, 16B-aligned rows

__global__ __launch_bounds__(256, 3) void hyper_conv_kernel(
    const float* __restrict__ x,        // [32][64][128][128]
    const float* __restrict__ w_all,    // [32][36864]  ([b][o][c][ky][kx])
    const float* __restrict__ bias_all, // [32][64]
    float* __restrict__ out)            // [32][64][128][128]
{
    __shared__ __align__(16) float sx[CC_][18][XPAD_];  // 11.25 KB
    __shared__ __align__(16) float sw[CC_][9][O_];      // 18 KB

    const int blk = blockIdx.x;           // 2048 = 32 samples * 64 tiles
    const int b   = blk >> 6;
    const int rem = blk & 63;
    const int y0  = (rem >> 3) << 4;      // tile origin
    const int x0  = (rem & 7) << 4;

    const int tid = threadIdx.x;
    const int o0  = (tid >> 5) << 3;      // 8 out-channel groups of 8
    const int pg  = tid & 31;             // 32 pixel groups
    const int ty  = pg >> 1;              // row in tile 0..15
    const int tx0 = (pg & 1) << 3;        // 0 or 8

    float acc[8][8];
    #pragma unroll
    for (int o = 0; o < 8; ++o)
        #pragma unroll
        for (int j = 0; j < 8; ++j) acc[o][j] = 0.f;

    const float* xb = x + (size_t)b * C_ * H_ * W_;
    const float* wb = w_all + (size_t)b * KU_;

    for (int cb = 0; cb < C_; cb += CC_) {
        __syncthreads();
        // ---- stage x halo tile: CC_ x 18 x 18 (zero-padded borders) ----
        for (int idx = tid; idx < CC_ * 18 * 18; idx += 256) {
            const int cc = idx / 324;
            const int r  = idx - cc * 324;
            const int yy = r / 18;
            const int xx = r - yy * 18;
            const int gy = y0 - 1 + yy;
            const int gx = x0 - 1 + xx;
            float v = 0.f;
            if ((unsigned)gy < (unsigned)H_ && (unsigned)gx < (unsigned)W_)
                v = xb[(size_t)(cb + cc) * H_ * W_ + gy * W_ + gx];
            sx[cc][yy][xx] = v;
        }
        // ---- stage weights transposed: sw[cc][k][o] ----
        for (int idx = tid; idx < CC_ * 9 * O_; idx += 256) {
            const int o  = idx / 72;
            const int r  = idx - o * 72;
            const int cc = r / 9;
            const int k  = r - cc * 9;
            sw[cc][k][o] = wb[o * (C_ * 9) + (cb + cc) * 9 + k];
        }
        __syncthreads();

        #pragma unroll
        for (int cc = 0; cc < CC_; ++cc) {
            #pragma unroll
            for (int ky = 0; ky < 3; ++ky) {
                // load 12 input values covering all 3 kx windows (aligned float4)
                const float4* xp4 =
                    reinterpret_cast<const float4*>(&sx[cc][ty + ky][tx0]);
                const float4 xa = xp4[0], xbv = xp4[1], xc = xp4[2];
                float xr[12];
                xr[0] = xa.x;  xr[1] = xa.y;  xr[2]  = xa.z;  xr[3]  = xa.w;
                xr[4] = xbv.x; xr[5] = xbv.y; xr[6]  = xbv.z; xr[7]  = xbv.w;
                xr[8] = xc.x;  xr[9] = xc.y;  xr[10] = xc.z;  xr[11] = xc.w;

                #pragma unroll
                for (int kx = 0; kx < 3; ++kx) {
                    const float4* wp4 =
                        reinterpret_cast<const float4*>(&sw[cc][ky * 3 + kx][o0]);
                    const float4 wa = wp4[0], wc = wp4[1];
                    float wv[8];
                    wv[0] = wa.x; wv[1] = wa.y; wv[2] = wa.z; wv[3] = wa.w;
                    wv[4] = wc.x; wv[5] = wc.y; wv[6] = wc.z; wv[7] = wc.w;
                    #pragma unroll
                    for (int o = 0; o < 8; ++o)
                        #pragma unroll
                        for (int j = 0; j < 8; ++j)
                            acc[o][j] += wv[o] * xr[kx + j];
                }
            }
        }
    }

    // ---- epilogue: add bias, coalesced float4 stores ----
    const float4* bp = reinterpret_cast<const float4*>(bias_all + b * O_ + o0);
    const float4 b0 = bp[0], b1 = bp[1];
    float bias[8] = {b0.x, b0.y, b0.z, b0.w, b1.x, b1.y, b1.z, b1.w};

    #pragma unroll
    for (int o = 0; o < 8; ++o) {
        float4* op = reinterpret_cast<float4*>(
            out + (((size_t)b * O_ + o0 + o) * H_ + (y0 + ty)) * W_ + x0 + tx0);
        float4 r0, r1;
        r0.x = acc[o][0] + bias[o]; r0.y = acc[o][1] + bias[o];
        r0.z = acc[o][2] + bias[o]; r0.w = acc[o][3] + bias[o];
        r1.x = acc[o][4] + bias[o]; r1.y = acc[o][5] + bias[o];
        r1.z = acc[o][6] + bias[o]; r1.w = acc[o][7] + bias[o];
        op[0] = r0; op[1] = r1;
    }
}

// ---------------------------------------------------------------------------
extern "C" void kernel_launch(void* const* d_in, const int* in_sizes, int n_in,
                              void* d_out, int out_size, void* d_ws, size_t ws_size,
                              hipStream_t stream) {
    const float* x   = (const float*)d_in[0];
    const float* hyp = (const float*)d_in[1];
    const float* Wk  = (const float*)d_in[2];
    const float* bk  = (const float*)d_in[3];
    const float* Wb  = (const float*)d_in[4];
    const float* bb  = (const float*)d_in[5];
    float* out = (float*)d_out;

    float* w_all    = (float*)d_ws;                       // 32*36864 f32
    float* bias_all = w_all + (size_t)B_ * KU_;           // 32*64 f32

    hyper_weights_kernel<<<KU_ / 256, 256, 0, stream>>>(hyp, Wk, bk, w_all);
    hyper_bias_kernel<<<(B_ * O_) / 256, 256, 0, stream>>>(hyp, Wb, bb, bias_all);
    hyper_conv_kernel<<<B_ * 64, 256, 0, stream>>>(x, w_all, bias_all, out);
}

// Round 5
// 356.454 us; speedup vs baseline: 2.4093x; 2.4093x over previous
//
#include <hip/hip_runtime.h>
#include <math.h>

#define B_    32
#define C_    64
#define O_    64
#define H_    128
#define W_    128
#define HW_   (H_ * W_)
#define HYP_  64

typedef __attribute__((ext_vector_type(8)))  short short8;   // 8 bf16 (4 VGPR)
typedef __attribute__((ext_vector_type(16))) float f32x16;   // MFMA 32x32 acc

// Weight-fragment workspace: per sample 144 fragments (4 ch * 9 kk * 2 og * 2 hi/lo)
// of 512 bf16 (64 lanes x 8 elems) = 73728 shorts. fid = ch*36 + kk*4 + og*2 (+1=lo).
// Lane l of fragment fid holds A[row=o][k=c_local]: o = og*32 + (l&31),
// c_local = 8*(l>>5) + e. NOTE: the k-map is A/B-symmetric on CDNA, and the x
// LDS layout uses the IDENTICAL map, so any HW k-permutation cancels in the
// MFMA's sum over k. C/D map is HW-verified (m74/m101).
#define WF_PER_B 73728

__device__ __forceinline__ unsigned short f2bf(float x) {   // RNE fp32->bf16
    unsigned u = __float_as_uint(x);
    return (unsigned short)((u + 0x7FFFu + ((u >> 16) & 1u)) >> 16);
}

// ---------------------------------------------------------------------------
// Kernel 1: hypernet weights -> tanh -> bf16 hi/lo, written in A-fragment order.
// gid enumerates (ch,kk,og,lane,e); consecutive tid => consecutive shorts.
// (ch,kk,og,lane,e) -> u is bijective over the 36864 kernel units.
// ---------------------------------------------------------------------------
__global__ __launch_bounds__(256) void hyper_weights_kernel(
    const float* __restrict__ hyp,   // [32][64]
    const float* __restrict__ Wk,    // [36864][64]
    const float* __restrict__ bk,    // [36864]
    short* __restrict__ wf)          // [32][73728]
{
    __shared__ float sh[8 * HYP_];
    const int tid = threadIdx.x;
    const int b0  = blockIdx.y * 8;
    for (int i = tid; i < 8 * HYP_; i += 256) sh[i] = hyp[b0 * HYP_ + i];
    __syncthreads();

    const int gid  = blockIdx.x * 256 + tid;    // 0..36863
    const int e    = gid & 7;
    const int lane = (gid >> 3) & 63;
    const int og   = (gid >> 9) & 1;
    const int kk   = (gid >> 10) % 9;
    const int ch   = (gid >> 10) / 9;
    const int o    = og * 32 + (lane & 31);
    const int c    = ch * 16 + ((lane >> 5) << 3) + e;
    const int u    = (o * C_ + c) * 9 + kk;               // kernel-unit index
    const int hi_idx = ((gid >> 9) << 10) + (gid & 511);  // fragment-major offset

    float wr[HYP_];
    const float4* wp = reinterpret_cast<const float4*>(Wk + (size_t)u * HYP_);
    #pragma unroll
    for (int i = 0; i < 16; ++i) {
        float4 v = wp[i];
        wr[4*i+0] = v.x; wr[4*i+1] = v.y; wr[4*i+2] = v.z; wr[4*i+3] = v.w;
    }
    const float bku = bk[u];

    #pragma unroll
    for (int b2 = 0; b2 < 8; ++b2) {
        const float* s = sh + b2 * HYP_;
        float a0 = bku, a1 = 0.f, a2 = 0.f, a3 = 0.f;
        #pragma unroll
        for (int h = 0; h < HYP_; h += 4) {
            a0 += s[h+0] * wr[h+0]; a1 += s[h+1] * wr[h+1];
            a2 += s[h+2] * wr[h+2]; a3 += s[h+3] * wr[h+3];
        }
        const float w = tanhf((a0 + a1) + (a2 + a3));
        const unsigned short h16 = f2bf(w);
        const float hf = __uint_as_float((unsigned)h16 << 16);
        const unsigned short l16 = f2bf(w - hf);
        short* dst = wf + (size_t)(b0 + b2) * WF_PER_B + hi_idx;
        dst[0]   = (short)h16;     // hi fragment
        dst[512] = (short)l16;     // lo fragment (+512 shorts = fid+1)
    }
}

// ---------------------------------------------------------------------------
// Kernel 2: per-sample bias  bias_all[b][o] = tanh(hyp[b]·Wb[o] + bb[o])
// ---------------------------------------------------------------------------
__global__ __launch_bounds__(256) void hyper_bias_kernel(
    const float* __restrict__ hyp, const float* __restrict__ Wb,
    const float* __restrict__ bb, float* __restrict__ bias_all)
{
    const int idx = blockIdx.x * 256 + threadIdx.x;   // 0..2047
    const int b = idx >> 6;
    const int o = idx & 63;
    const float* hp = hyp + b * HYP_;
    const float* wp = Wb + o * HYP_;
    float acc = bb[o];
    #pragma unroll
    for (int h = 0; h < HYP_; ++h) acc += hp[h] * wp[h];
    bias_all[idx] = tanhf(acc);
}

// ---------------------------------------------------------------------------
// Kernel 3: per-sample 3x3 conv via bf16 MFMA 32x32x16 (hi/lo = fp32-grade:
// hh + lh + hl terms, dropping ll ~2^-17 rel). Block = 256 thr (4 waves) =
// (sample, 16x32 tile); all 64 out-channels. x staged hi/lo in double-buffered
// swizzled LDS; weight A-fragments streamed from L2 (wf).
// Balance per (kk,pf): 2 ds_read_b128 (24 CU-cyc) : 6 MFMA (48 CU-cyc) ->
// MFMA-bound with ~50% LDS-pipe load.
// ---------------------------------------------------------------------------
#define TILE_H 16
#define TILE_W 32
#define HALO_W 34
#define NREG   612              // 18*34 halo points
#define XLO    19584            // NREG*32 bytes (hi area size)
#define BUFSZ  39168            // hi+lo per buffer

// region R holds 16 c-contiguous bf16 (32B). XOR slot-swizzle (bijective:
// bit7=R2, bit6=R1^R2, bit5=R0^R1, bit4=g^R0 — triangular).
__device__ __forceinline__ int xs_addr(int R, int g) {
    return ((R << 5) + (g << 4)) ^ ((R & 7) << 4);
}

__device__ __forceinline__ short8 ldfrag(const short* p, int fid, int ln) {
    return *reinterpret_cast<const short8*>(p + (((size_t)fid << 6) + ln) * 8);
}

__device__ __forceinline__ void load_pre(float pre[3][16], const float* xb,
                                         int cb, const int* s_off, const bool* s_ok) {
    #pragma unroll
    for (int it = 0; it < 3; ++it)
        #pragma unroll
        for (int c = 0; c < 16; ++c)
            pre[it][c] = s_ok[it] ? xb[(size_t)(cb + c) * HW_ + s_off[it]] : 0.f;
}

__device__ __forceinline__ void stage_x(char* buf, const float pre[3][16], int tid) {
    #pragma unroll
    for (int it = 0; it < 3; ++it) {
        const int R = tid + it * 256;
        if (R < NREG) {
            short8 vh0, vh1, vl0, vl1;
            #pragma unroll
            for (int c = 0; c < 16; ++c) {
                const unsigned short h = f2bf(pre[it][c]);
                const float hf = __uint_as_float((unsigned)h << 16);
                const short lo = (short)f2bf(pre[it][c] - hf);
                if (c < 8) { vh0[c]     = (short)h; vl0[c]     = lo; }
                else       { vh1[c - 8] = (short)h; vl1[c - 8] = lo; }
            }
            const int a0 = xs_addr(R, 0), a1 = xs_addr(R, 1);
            *(short8*)(buf + a0)       = vh0;
            *(short8*)(buf + a1)       = vh1;
            *(short8*)(buf + XLO + a0) = vl0;
            *(short8*)(buf + XLO + a1) = vl1;
        }
    }
}

__global__ __launch_bounds__(256, 2) void hyper_conv_mfma(
    const float* __restrict__ x,        // [32][64][128][128]
    const short* __restrict__ wf,       // [32][73728] A-fragments
    const float* __restrict__ bias_all, // [32][64]
    float* __restrict__ out)            // [32][64][128][128]
{
    __shared__ __align__(16) char lds[2 * BUFSZ];   // 78336 B -> 2 blocks/CU

    const int tid = threadIdx.x;
    const int wv  = tid >> 6;        // wave -> rows 4*wv..4*wv+3
    const int ln  = tid & 63;
    const int p   = ln & 31;         // pixel col in fragment
    const int g   = ln >> 5;         // k-half (c 8g..8g+7)

    const int blk = blockIdx.x;      // 1024 = 32 samples * 32 tiles
    const int b   = blk >> 5;
    const int t   = blk & 31;
    const int y0  = (t >> 2) * TILE_H;
    const int x0  = (t & 3) * TILE_W;

    const float* xb  = x  + (size_t)b * C_ * HW_;
    const short* wfb = wf + (size_t)b * WF_PER_B;

    f32x16 acc[2][4];
    #pragma unroll
    for (int og = 0; og < 2; ++og)
        #pragma unroll
        for (int pf = 0; pf < 4; ++pf)
            #pragma unroll
            for (int r = 0; r < 16; ++r) acc[og][pf][r] = 0.f;

    int  s_off[3]; bool s_ok[3];
    #pragma unroll
    for (int it = 0; it < 3; ++it) {
        const int R  = tid + it * 256;
        const int yy = R / HALO_W;
        const int xx = R - yy * HALO_W;
        const int gy = y0 + yy - 1, gx = x0 + xx - 1;
        s_ok[it]  = (R < NREG) && ((unsigned)gy < (unsigned)H_) &&
                    ((unsigned)gx < (unsigned)W_);
        s_off[it] = s_ok[it] ? (gy * W_ + gx) : 0;
    }

    const int R0base = (4 * wv) * HALO_W + p;

    float pre[3][16];
    load_pre(pre, xb, 0, s_off, s_ok);          // chunk 0
    stage_x(lds, pre, tid);                     // -> buf0
    load_pre(pre, xb, 16, s_off, s_ok);         // chunk 1 (in regs, T14)
    __syncthreads();                            // buf0 visible

    for (int ch = 0; ch < 4; ++ch) {
        char* cur = lds + (ch & 1) * BUFSZ;
        // stage next chunk into the other buffer (its readers finished at the
        // previous barrier), then prefetch chunk ch+2 into registers (T14).
        if (ch < 3) stage_x(lds + ((ch + 1) & 1) * BUFSZ, pre, tid);
        if (ch < 2) load_pre(pre, xb, (ch + 2) * 16, s_off, s_ok);

        const int fb = ch * 36;
        short8 ah[2], al[2], nh[2], nl[2];
        #pragma unroll
        for (int og = 0; og < 2; ++og) {
            ah[og] = ldfrag(wfb, fb + og * 2,     ln);
            al[og] = ldfrag(wfb, fb + og * 2 + 1, ln);
        }
        #pragma unroll
        for (int kk = 0; kk < 9; ++kk) {
            if (kk < 8) {   // prefetch next k-step's weight frags (L2-resident)
                #pragma unroll
                for (int og = 0; og < 2; ++og) {
                    nh[og] = ldfrag(wfb, fb + (kk + 1) * 4 + og * 2,     ln);
                    nl[og] = ldfrag(wfb, fb + (kk + 1) * 4 + og * 2 + 1, ln);
                }
            }
            const int dk = (kk / 3) * HALO_W + (kk % 3);
            __builtin_amdgcn_s_setprio(1);                       // T5
            #pragma unroll
            for (int pf = 0; pf < 4; ++pf) {
                const int ad = xs_addr(R0base + pf * HALO_W + dk, g);
                const short8 bh = *(const short8*)(cur + ad);
                const short8 bl = *(const short8*)(cur + XLO + ad);
                #pragma unroll
                for (int og = 0; og < 2; ++og) {
                    acc[og][pf] = __builtin_amdgcn_mfma_f32_32x32x16_bf16(
                        ah[og], bh, acc[og][pf], 0, 0, 0);
                    acc[og][pf] = __builtin_amdgcn_mfma_f32_32x32x16_bf16(
                        al[og], bh, acc[og][pf], 0, 0, 0);
                    acc[og][pf] = __builtin_amdgcn_mfma_f32_32x32x16_bf16(
                        ah[og], bl, acc[og][pf], 0, 0, 0);
                }
            }
            __builtin_amdgcn_s_setprio(0);
            #pragma unroll
            for (int og = 0; og < 2; ++og) { ah[og] = nh[og]; al[og] = nl[og]; }
        }
        __syncthreads();
    }

    // epilogue: C/D layout col=ln&31, row=(r&3)+8*(r>>2)+4*(ln>>5)  [m74/m101]
    const float* bs = bias_all + b * O_;
    #pragma unroll
    for (int og = 0; og < 2; ++og) {
        float bv[16];
        #pragma unroll
        for (int r = 0; r < 16; ++r)
            bv[r] = bs[og * 32 + (r & 3) + ((r >> 2) << 3) + (g << 2)];
        #pragma unroll
        for (int pf = 0; pf < 4; ++pf) {
            const int row = y0 + 4 * wv + pf;
            #pragma unroll
            for (int r = 0; r < 16; ++r) {
                const int o = og * 32 + (r & 3) + ((r >> 2) << 3) + (g << 2);
                out[((size_t)b * O_ + o) * HW_ + row * W_ + x0 + p] =
                    acc[og][pf][r] + bv[r];
            }
        }
    }
}

// ---------------------------------------------------------------------------
extern "C" void kernel_launch(void* const* d_in, const int* in_sizes, int n_in,
                              void* d_out, int out_size, void* d_ws, size_t ws_size,
                              hipStream_t stream) {
    const float* x   = (const float*)d_in[0];
    const float* hyp = (const float*)d_in[1];
    const float* Wk  = (const float*)d_in[2];
    const float* bk  = (const float*)d_in[3];
    const float* Wb  = (const float*)d_in[4];
    const float* bb  = (const float*)d_in[5];
    float* out = (float*)d_out;

    short* wf       = (short*)d_ws;                               // 4.72 MB
    float* bias_all = (float*)((char*)d_ws + (size_t)B_ * WF_PER_B * 2);

    hyper_weights_kernel<<<dim3(144, 4), 256, 0, stream>>>(hyp, Wk, bk, wf);
    hyper_bias_kernel<<<8, 256, 0, stream>>>(hyp, Wb, bb, bias_all);
    hyper_conv_mfma<<<1024, 256, 0, stream>>>(x, wf, bias_all, out);
}